// Round 11
// baseline (364.533 us; speedup 1.0000x reference)
//
#include <hip/hip_runtime.h>
#include <math.h>

#define NNODES   50000
#define NFEAT    512
#define NCLASS   256
#define NEG_SLOPE 0.2f
#define GBLK     391     // gemm-role blocks: 391 * 128 rows = 50048
#define SBLK     391     // scatter-role blocks (placed first)
#define BCAP     64      // per-row bucket capacity; P(deg>64) ~ 1e-18/row

typedef __attribute__((ext_vector_type(8))) short short8;
typedef __attribute__((ext_vector_type(4))) float floatx4;

__device__ __forceinline__ unsigned short f2bf(float f) {
    unsigned u = __builtin_bit_cast(unsigned, f);
    u += 0x7fffu + ((u >> 16) & 1u);          // RNE
    return (unsigned short)(u >> 16);
}
__device__ __forceinline__ float bf2f_lo(unsigned u) {
    return __builtin_bit_cast(float, u << 16);
}
__device__ __forceinline__ float bf2f_hi(unsigned u) {
    return __builtin_bit_cast(float, u & 0xffff0000u);
}
// pack two floats -> (bf16(lo) | bf16(hi)<<16), round-half-away
__device__ __forceinline__ unsigned pack_bf16_rh(float lo, float hi) {
    const unsigned ulo = __builtin_bit_cast(unsigned, lo) + 0x8000u;
    const unsigned uhi = __builtin_bit_cast(unsigned, hi) + 0x8000u;
    return __builtin_amdgcn_perm(uhi, ulo, 0x07060302);
}

#if __has_builtin(__builtin_amdgcn_fdot2_f32_bf16)
#define HAVE_DOT2 1
typedef __attribute__((ext_vector_type(2))) __bf16 bfx2;
__device__ __forceinline__ float dot2bf(unsigned hpair, unsigned epair, float acc) {
    return __builtin_amdgcn_fdot2_f32_bf16(__builtin_bit_cast(bfx2, hpair),
                                           __builtin_bit_cast(bfx2, epair), acc, false);
}
#endif

// ---------------------------------------------------------------------------
// Init: W [512][256] fp32 -> Wt [256][512] bf16 transposed; zero cursor.
// ---------------------------------------------------------------------------
__global__ __launch_bounds__(256) void init_kernel(const float* __restrict__ W,
                                                   unsigned short* __restrict__ Wt,
                                                   int* __restrict__ cursor, int zn) {
    const int i = blockIdx.x * 256 + threadIdx.x;     // 0..131071
    const int n = i >> 9;
    const int k = i & 511;
    Wt[i] = f2bf(W[(size_t)k * NCLASS + n]);
    if (i < zn) cursor[i] = 0;
}

// ---------------------------------------------------------------------------
// Fused heterogeneous dispatch: 782 blocks = 391 scatter (first) + 391 gemm.
// GEMM tile = 128x256 (vs R10's 64x256): halves the L2-resident B re-read
// from 200 MB to 100 MB. Model (R10 post-mortem): gemm is bound by total
// L1-port traffic (A 102 + B + writes 26 MB); R2's 68us = 79% of the
// 6.1 TB/s chip port ceiling, so B-demand is the only reducible term.
// Gemm body = R2's verified dbuf pipeline with the A-stage doubled (two
// 16-row chunks per wave) + R0's verified 4-pass acc[4][8] epilogue.
// LDS 48KB -> 3 blocks/CU; launch_bounds(256,3) caps VGPR at ~170.
// ---------------------------------------------------------------------------
__global__ __launch_bounds__(256, 3) void gemm_scatter_kernel(const float* __restrict__ x,
                                                              const unsigned short* __restrict__ Wt,
                                                              unsigned short* __restrict__ hb,
                                                              const float* __restrict__ a,
                                                              float* __restrict__ s_row,
                                                              float* __restrict__ s_col,
                                                              const int* __restrict__ erow,
                                                              const int* __restrict__ ecol,
                                                              int* __restrict__ cursor,
                                                              int* __restrict__ bucket,
                                                              int M, int E) {
    __shared__ union {
        struct { short As[2][128 * 32]; short Bs[2][256 * 32]; } k;  // 16KB + 32KB = 48KB
        short Cs[32 * 260];                                          // 16.6KB (epilogue)
    } u;

    const int bid = blockIdx.x;
    const int tid = threadIdx.x;

    if (bid < SBLK) {
        // ---------------- scatter role (VERIFIED logic, grid-stride) -------
        const int stride = SBLK * 256;
        for (int i = bid * 256 + tid; i < E; i += stride) {
            const int r = erow[i];
            const int c = ecol[i];
            const int pos = atomicAdd(&cursor[r], 1);
            if (pos < BCAP) bucket[((size_t)r << 6) + pos] = c;
        }
        return;
    }

    // ---------------- gemm role: 128x256 tile, R2 pipeline ----------------
    const int w    = tid >> 6;
    const int lane = tid & 63;
    const int rowbase = (bid - SBLK) * 128;

    const int wm = w & 1;     // 64-row half
    const int wn = w >> 1;    // 128-col half
    const int srow = lane >> 2;
    const int skq  = (lane & 3) << 3;
    const int fm = lane & 15;
    const int fq = lane >> 4;

    floatx4 acc[4][8];
#pragma unroll
    for (int i = 0; i < 4; ++i)
#pragma unroll
        for (int j = 0; j < 8; ++j)
            acc[i][j] = (floatx4){0.f, 0.f, 0.f, 0.f};

    // A-staging: wave w owns 32 rows [w*32, w*32+32) as two 16-row chunks
    // (each chunk = R2's verified pattern: row lane>>2, k-chunk (lane&3)*8).
    const int ar0 = min(rowbase + w * 32 + srow, M - 1);
    const int ar1 = min(rowbase + w * 32 + 16 + srow, M - 1);
    const size_t ab0 = (size_t)ar0 * NFEAT + skq;
    const size_t ab1 = (size_t)ar1 * NFEAT + skq;
    const int lr0 = (w * 32 + srow) * 32 + skq;        // halfword offset in As[buf]
    const int lr1 = (w * 32 + 16 + srow) * 32 + skq;

    // B-staging (VERIFIED R2 macro): wave w stages segs 4w..4w+3.
#define STAGE_B(buf, k0)                                                                      \
    {                                                                                         \
        _Pragma("unroll")                                                                     \
        for (int t = 0; t < 4; ++t) {                                                         \
            const int seg = w * 4 + t;                                                        \
            const int nr  = seg * 16 + srow;                                                  \
            __builtin_amdgcn_global_load_lds(                                                 \
                (const __attribute__((address_space(1))) void*)(Wt + (size_t)nr * NFEAT + (k0) + skq), \
                (__attribute__((address_space(3))) void*)(&u.k.Bs[buf][seg * 512]), 16, 0, 0); \
        }                                                                                     \
    }

#define PACK_A(dst_off, srcp)                                                                 \
    {                                                                                         \
        const float4 u0 = (srcp)[0];                                                          \
        const float4 u1 = (srcp)[1];                                                          \
        uint4 o;                                                                              \
        o.x = pack_bf16_rh(u0.x, u0.y);                                                       \
        o.y = pack_bf16_rh(u0.z, u0.w);                                                       \
        o.z = pack_bf16_rh(u1.x, u1.y);                                                       \
        o.w = pack_bf16_rh(u1.z, u1.w);                                                       \
        *(uint4*)&u.k.As[0][dst_off] = o;                                                     \
    }

    // ---- prologue: fill buffer 0 with k0=0 ----
    STAGE_B(0, 0)
    PACK_A(lr0, (const float4*)&x[ab0])
    PACK_A(lr1, (const float4*)&x[ab1])
    __syncthreads();

    int cur = 0;
    for (int k0 = 0; k0 < NFEAT; k0 += 32) {
        const int nxt = cur ^ 1;
        const bool have_next = (k0 + 32) < NFEAT;
        float4 p0, p1, q0, q1;
        if (have_next) {
            // Issue next tile's loads FIRST so latency hides under MFMA.
            const float4* xp0 = (const float4*)&x[ab0 + k0 + 32];
            const float4* xp1 = (const float4*)&x[ab1 + k0 + 32];
            p0 = xp0[0];
            p1 = xp0[1];
            q0 = xp1[0];
            q1 = xp1[1];
            STAGE_B(nxt, k0 + 32)
        }

        short8 af[4];
#pragma unroll
        for (int mt = 0; mt < 4; ++mt)
            af[mt] = *(const short8*)&u.k.As[cur][(wm * 64 + mt * 16 + fm) * 32 + fq * 8];
#pragma unroll
        for (int nt = 0; nt < 8; ++nt) {
            const short8 bfr = *(const short8*)&u.k.Bs[cur][(wn * 128 + nt * 16 + fm) * 32 + fq * 8];
#pragma unroll
            for (int mt = 0; mt < 4; ++mt)
                acc[mt][nt] = __builtin_amdgcn_mfma_f32_16x16x32_bf16(af[mt], bfr, acc[mt][nt], 0, 0, 0);
        }

        if (have_next) {
            uint4 o;
            o.x = pack_bf16_rh(p0.x, p0.y);
            o.y = pack_bf16_rh(p0.z, p0.w);
            o.z = pack_bf16_rh(p1.x, p1.y);
            o.w = pack_bf16_rh(p1.z, p1.w);
            *(uint4*)&u.k.As[nxt][lr0] = o;
            uint4 o2;
            o2.x = pack_bf16_rh(q0.x, q0.y);
            o2.y = pack_bf16_rh(q0.z, q0.w);
            o2.z = pack_bf16_rh(q1.x, q1.y);
            o2.w = pack_bf16_rh(q1.z, q1.w);
            *(uint4*)&u.k.As[nxt][lr1] = o2;
        }
        __syncthreads();   // drains vmcnt (B lds) + lgkmcnt (A write) for nxt
        cur = nxt;
    }

    // Epilogue (VERIFIED R0 4-pass): passes p=0..3 over 32-row groups.
    // Wave wm covers rows wm*64 + mt*16; pass p rows = (p>>1)*64 + (p&1)*32.
#pragma unroll
    for (int p = 0; p < 4; ++p) {
        __syncthreads();
        if ((w & 1) == (p >> 1)) {
#pragma unroll
            for (int mt2 = 0; mt2 < 2; ++mt2) {
                const int mt = (p & 1) * 2 + mt2;
#pragma unroll
                for (int nt = 0; nt < 8; ++nt)
#pragma unroll
                    for (int r = 0; r < 4; ++r)
                        u.Cs[(mt2 * 16 + fq * 4 + r) * 260 + wn * 128 + nt * 16 + fm] =
                            (short)f2bf(acc[mt][nt][r]);
            }
        }
        __syncthreads();
        // 32 rows x 256 cols: one wave handles one row/iter
#pragma unroll
        for (int kk = 0; kk < 8; ++kk) {
            const int idx = tid + kk * 256;
            const int lrow = idx >> 6;
            const int c4 = (idx & 63) << 2;
            const int grow = rowbase + p * 32 + lrow;
            const uint2 vv = *(const uint2*)&u.Cs[lrow * 260 + c4];
            const float f0 = bf2f_lo(vv.x), f1 = bf2f_hi(vv.x);
            const float f2 = bf2f_lo(vv.y), f3 = bf2f_hi(vv.y);
            const float4 A1 = *(const float4*)&a[c4];
            const float4 A2 = *(const float4*)&a[NCLASS + c4];
            float p1 = f0 * A1.x + f1 * A1.y + f2 * A1.z + f3 * A1.w;
            float p2 = f0 * A2.x + f1 * A2.y + f2 * A2.z + f3 * A2.w;
#pragma unroll
            for (int off = 1; off < 64; off <<= 1) {
                p1 += __shfl_xor(p1, off);
                p2 += __shfl_xor(p2, off);
            }
            if (grow < M) {
                *(uint2*)&hb[(size_t)grow * NCLASS + c4] = vv;
                if (lane == 0) {
                    s_row[grow] = p1;
                    s_col[grow] = p2;
                }
            }
        }
    }
}

// ---------------------------------------------------------------------------
// Aggregation + elu + log_softmax (VERIFIED). One wave per row; lane holds
// 4 features. e = exp(-lrelu(s_row[r] + s_col[c])) inline.
// ---------------------------------------------------------------------------
__global__ __launch_bounds__(256) void aggregate_kernel(const unsigned short* __restrict__ hb,
                                                        const int* __restrict__ bucket,
                                                        const int* __restrict__ cnt,
                                                        const float* __restrict__ s_row,
                                                        const float* __restrict__ s_col,
                                                        float* __restrict__ out, int n) {
    const int wave = (int)((blockIdx.x * (size_t)blockDim.x + threadIdx.x) >> 6);
    const int lane = threadIdx.x & 63;
    if (wave >= n) return;
    const int r = wave;
    const int jb = r << 6;
    const int je = jb + min(cnt[r], BCAP);
    const int fo = lane << 2;
    const float sr = s_row[r];

    float rowsum = 0.f;
    int j = jb;

#define EDGE_E(c) ({ const float _l = sr + s_col[c];                         \
                     const float _lr = _l > 0.f ? _l : NEG_SLOPE * _l;       \
                     __expf(-_lr); })

#ifdef HAVE_DOT2
    float ac0 = 0.f, ac1 = 0.f, ac2 = 0.f, ac3 = 0.f;
    for (; j + 3 < je; j += 4) {
        const int4 cv = *(const int4*)&bucket[j];
        const uint2 g0 = *(const uint2*)&hb[(size_t)cv.x * NCLASS + fo];
        const uint2 g1 = *(const uint2*)&hb[(size_t)cv.y * NCLASS + fo];
        const uint2 g2 = *(const uint2*)&hb[(size_t)cv.z * NCLASS + fo];
        const uint2 g3 = *(const uint2*)&hb[(size_t)cv.w * NCLASS + fo];
        const float e0 = EDGE_E(cv.x);
        const float e1 = EDGE_E(cv.y);
        const float e2 = EDGE_E(cv.z);
        const float e3 = EDGE_E(cv.w);
        const unsigned ep01 = pack_bf16_rh(e0, e1);
        const unsigned ep23 = pack_bf16_rh(e2, e3);
        rowsum += (e0 + e1) + (e2 + e3);
        ac0 = dot2bf(__builtin_amdgcn_perm(g1.x, g0.x, 0x05040100), ep01, ac0);
        ac1 = dot2bf(__builtin_amdgcn_perm(g1.x, g0.x, 0x07060302), ep01, ac1);
        ac2 = dot2bf(__builtin_amdgcn_perm(g1.y, g0.y, 0x05040100), ep01, ac2);
        ac3 = dot2bf(__builtin_amdgcn_perm(g1.y, g0.y, 0x07060302), ep01, ac3);
        ac0 = dot2bf(__builtin_amdgcn_perm(g3.x, g2.x, 0x05040100), ep23, ac0);
        ac1 = dot2bf(__builtin_amdgcn_perm(g3.x, g2.x, 0x07060302), ep23, ac1);
        ac2 = dot2bf(__builtin_amdgcn_perm(g3.y, g2.y, 0x05040100), ep23, ac2);
        ac3 = dot2bf(__builtin_amdgcn_perm(g3.y, g2.y, 0x07060302), ep23, ac3);
    }
    float4 acc = make_float4(ac0, ac1, ac2, ac3);
#else
    float4 acc = make_float4(0.f, 0.f, 0.f, 0.f);
    for (; j + 3 < je; j += 4) {
        const int4 cv = *(const int4*)&bucket[j];
        const uint2 g0 = *(const uint2*)&hb[(size_t)cv.x * NCLASS + fo];
        const uint2 g1 = *(const uint2*)&hb[(size_t)cv.y * NCLASS + fo];
        const uint2 g2 = *(const uint2*)&hb[(size_t)cv.z * NCLASS + fo];
        const uint2 g3 = *(const uint2*)&hb[(size_t)cv.w * NCLASS + fo];
        const float e0 = EDGE_E(cv.x);
        const float e1 = EDGE_E(cv.y);
        const float e2 = EDGE_E(cv.z);
        const float e3 = EDGE_E(cv.w);
        rowsum += (e0 + e1) + (e2 + e3);
        acc.x += e0 * bf2f_lo(g0.x) + e1 * bf2f_lo(g1.x) + e2 * bf2f_lo(g2.x) + e3 * bf2f_lo(g3.x);
        acc.y += e0 * bf2f_hi(g0.x) + e1 * bf2f_hi(g1.x) + e2 * bf2f_hi(g2.x) + e3 * bf2f_hi(g3.x);
        acc.z += e0 * bf2f_lo(g0.y) + e1 * bf2f_lo(g1.y) + e2 * bf2f_lo(g2.y) + e3 * bf2f_lo(g3.y);
        acc.w += e0 * bf2f_hi(g0.y) + e1 * bf2f_hi(g1.y) + e2 * bf2f_hi(g2.y) + e3 * bf2f_hi(g3.y);
    }
#endif
    for (; j < je; ++j) {
        const int c = bucket[j];
        const uint2 g = *(const uint2*)&hb[(size_t)c * NCLASS + fo];
        const float e = EDGE_E(c);
        rowsum += e;
        acc.x += e * bf2f_lo(g.x);
        acc.y += e * bf2f_hi(g.x);
        acc.z += e * bf2f_lo(g.y);
        acc.w += e * bf2f_hi(g.y);
    }

    const float inv = 1.f / rowsum;
    float v[4] = {acc.x * inv, acc.y * inv, acc.z * inv, acc.w * inv};
#pragma unroll
    for (int i = 0; i < 4; ++i)
        v[i] = v[i] > 0.f ? v[i] : __expf(v[i]) - 1.f;

    float m = fmaxf(fmaxf(v[0], v[1]), fmaxf(v[2], v[3]));
#pragma unroll
    for (int off = 32; off > 0; off >>= 1) m = fmaxf(m, __shfl_xor(m, off));
    float s = 0.f;
#pragma unroll
    for (int i = 0; i < 4; ++i) s += __expf(v[i] - m);
#pragma unroll
    for (int off = 32; off > 0; off >>= 1) s += __shfl_xor(s, off);
    const float lse = m + __logf(s);

    float4 o = make_float4(v[0] - lse, v[1] - lse, v[2] - lse, v[3] - lse);
    *(float4*)&out[(size_t)r * NCLASS + fo] = o;
}

// ---------------------------------------------------------------------------
extern "C" void kernel_launch(void* const* d_in, const int* in_sizes, int n_in,
                              void* d_out, int out_size, void* d_ws, size_t ws_size,
                              hipStream_t stream) {
    const float* x  = (const float*)d_in[0];
    const float* W  = (const float*)d_in[1];
    const float* a  = (const float*)d_in[2];
    const int* edge = (const int*)d_in[3];
    float* out = (float*)d_out;

    const int M = in_sizes[0] / NFEAT;         // 50000
    const int E = in_sizes[3] / 2;             // 850000
    const int* row = edge;
    const int* col = edge + E;

    char* ws = (char*)d_ws;
    size_t off = 0;
    auto carve = [&](size_t bytes) -> char* {
        char* p = ws + off;
        off = (off + bytes + 255) & ~(size_t)255;
        return p;
    };
    unsigned short* Wt = (unsigned short*)carve((size_t)NCLASS * NFEAT * sizeof(short));
    unsigned short* hb = (unsigned short*)carve((size_t)M * NCLASS * sizeof(short)); // 25.6MB
    int*   cursor   = (int*)carve((size_t)M * sizeof(int));
    float* s_row    = (float*)carve((size_t)M * sizeof(float));
    float* s_col    = (float*)carve((size_t)M * sizeof(float));
    int*   bucket   = (int*)carve((size_t)M * BCAP * sizeof(int));   // 12.8MB

    init_kernel<<<512, 256, 0, stream>>>(W, Wt, cursor, M);

    gemm_scatter_kernel<<<SBLK + GBLK, 256, 0, stream>>>(x, Wt, hb, a, s_row, s_col,
                                                         row, col, cursor, bucket, M, E);

    aggregate_kernel<<<(M + 3) / 4, 256, 0, stream>>>(hb, bucket, cursor, s_row, s_col, out, M);
}

// Round 12
// 279.441 us; speedup vs baseline: 1.3045x; 1.3045x over previous
//
#include <hip/hip_runtime.h>
#include <math.h>

#define NNODES   50000
#define NFEAT    512
#define NCLASS   256
#define NEG_SLOPE 0.2f
#define GBLK     391     // gemm-role blocks: 391 * 128 rows = 50048
#define SBLK     391     // scatter-role blocks (placed first)
#define BCAP     64      // per-row bucket capacity; P(deg>64) ~ 1e-18/row

typedef __attribute__((ext_vector_type(8))) short short8;
typedef __attribute__((ext_vector_type(4))) float floatx4;

__device__ __forceinline__ unsigned short f2bf(float f) {
    unsigned u = __builtin_bit_cast(unsigned, f);
    u += 0x7fffu + ((u >> 16) & 1u);          // RNE
    return (unsigned short)(u >> 16);
}
__device__ __forceinline__ float bf2f_lo(unsigned u) {
    return __builtin_bit_cast(float, u << 16);
}
__device__ __forceinline__ float bf2f_hi(unsigned u) {
    return __builtin_bit_cast(float, u & 0xffff0000u);
}
// pack two floats -> (bf16(lo) | bf16(hi)<<16), round-half-away
__device__ __forceinline__ unsigned pack_bf16_rh(float lo, float hi) {
    const unsigned ulo = __builtin_bit_cast(unsigned, lo) + 0x8000u;
    const unsigned uhi = __builtin_bit_cast(unsigned, hi) + 0x8000u;
    return __builtin_amdgcn_perm(uhi, ulo, 0x07060302);
}

#if __has_builtin(__builtin_amdgcn_fdot2_f32_bf16)
#define HAVE_DOT2 1
typedef __attribute__((ext_vector_type(2))) __bf16 bfx2;
__device__ __forceinline__ float dot2bf(unsigned hpair, unsigned epair, float acc) {
    return __builtin_amdgcn_fdot2_f32_bf16(__builtin_bit_cast(bfx2, hpair),
                                           __builtin_bit_cast(bfx2, epair), acc, false);
}
#endif

// ---------------------------------------------------------------------------
// Init: W [512][256] fp32 -> Wt [256][512] bf16 transposed; zero cursor.
// ---------------------------------------------------------------------------
__global__ __launch_bounds__(256) void init_kernel(const float* __restrict__ W,
                                                   unsigned short* __restrict__ Wt,
                                                   int* __restrict__ cursor, int zn) {
    const int i = blockIdx.x * 256 + threadIdx.x;     // 0..131071
    const int n = i >> 9;
    const int k = i & 511;
    Wt[i] = f2bf(W[(size_t)k * NCLASS + n]);
    if (i < zn) cursor[i] = 0;
}

// ---------------------------------------------------------------------------
// Fused heterogeneous dispatch: 782 blocks = 391 scatter (first) + 391 gemm.
// GEMM tile = 128x256: halves L2-resident B re-read (200 -> 100 MB).
// R11 FAILED with __launch_bounds__(256,3): VGPR cap 170 < acc[4][8]=128 +
// working set -> compiler spilled acc to scratch (VGPR_Count 84, WRITE_SIZE
// +72 MB, 181us). THIS ROUND: (256,2) -> cap 256, acc stays in the unified
// VGPR/AGPR file (R0 precedent: same tile at (256,2) reported 128 VGPR,
// no spill). Everything else byte-identical to R11.
// ---------------------------------------------------------------------------
__global__ __launch_bounds__(256, 2) void gemm_scatter_kernel(const float* __restrict__ x,
                                                              const unsigned short* __restrict__ Wt,
                                                              unsigned short* __restrict__ hb,
                                                              const float* __restrict__ a,
                                                              float* __restrict__ s_row,
                                                              float* __restrict__ s_col,
                                                              const int* __restrict__ erow,
                                                              const int* __restrict__ ecol,
                                                              int* __restrict__ cursor,
                                                              int* __restrict__ bucket,
                                                              int M, int E) {
    __shared__ union {
        struct { short As[2][128 * 32]; short Bs[2][256 * 32]; } k;  // 16KB + 32KB = 48KB
        short Cs[32 * 260];                                          // 16.6KB (epilogue)
    } u;

    const int bid = blockIdx.x;
    const int tid = threadIdx.x;

    if (bid < SBLK) {
        // ---------------- scatter role (VERIFIED logic, grid-stride) -------
        const int stride = SBLK * 256;
        for (int i = bid * 256 + tid; i < E; i += stride) {
            const int r = erow[i];
            const int c = ecol[i];
            const int pos = atomicAdd(&cursor[r], 1);
            if (pos < BCAP) bucket[((size_t)r << 6) + pos] = c;
        }
        return;
    }

    // ---------------- gemm role: 128x256 tile, R2 pipeline ----------------
    const int w    = tid >> 6;
    const int lane = tid & 63;
    const int rowbase = (bid - SBLK) * 128;

    const int wm = w & 1;     // 64-row half
    const int wn = w >> 1;    // 128-col half
    const int srow = lane >> 2;
    const int skq  = (lane & 3) << 3;
    const int fm = lane & 15;
    const int fq = lane >> 4;

    floatx4 acc[4][8];
#pragma unroll
    for (int i = 0; i < 4; ++i)
#pragma unroll
        for (int j = 0; j < 8; ++j)
            acc[i][j] = (floatx4){0.f, 0.f, 0.f, 0.f};

    // A-staging: wave w owns 32 rows [w*32, w*32+32) as two 16-row chunks
    // (each chunk = R2's verified pattern: row lane>>2, k-chunk (lane&3)*8).
    const int ar0 = min(rowbase + w * 32 + srow, M - 1);
    const int ar1 = min(rowbase + w * 32 + 16 + srow, M - 1);
    const size_t ab0 = (size_t)ar0 * NFEAT + skq;
    const size_t ab1 = (size_t)ar1 * NFEAT + skq;
    const int lr0 = (w * 32 + srow) * 32 + skq;        // halfword offset in As[buf]
    const int lr1 = (w * 32 + 16 + srow) * 32 + skq;

    // B-staging (VERIFIED R2 macro): wave w stages segs 4w..4w+3.
#define STAGE_B(buf, k0)                                                                      \
    {                                                                                         \
        _Pragma("unroll")                                                                     \
        for (int t = 0; t < 4; ++t) {                                                         \
            const int seg = w * 4 + t;                                                        \
            const int nr  = seg * 16 + srow;                                                  \
            __builtin_amdgcn_global_load_lds(                                                 \
                (const __attribute__((address_space(1))) void*)(Wt + (size_t)nr * NFEAT + (k0) + skq), \
                (__attribute__((address_space(3))) void*)(&u.k.Bs[buf][seg * 512]), 16, 0, 0); \
        }                                                                                     \
    }

#define PACK_A(dst_off, srcp)                                                                 \
    {                                                                                         \
        const float4 u0 = (srcp)[0];                                                          \
        const float4 u1 = (srcp)[1];                                                          \
        uint4 o;                                                                              \
        o.x = pack_bf16_rh(u0.x, u0.y);                                                       \
        o.y = pack_bf16_rh(u0.z, u0.w);                                                       \
        o.z = pack_bf16_rh(u1.x, u1.y);                                                       \
        o.w = pack_bf16_rh(u1.z, u1.w);                                                       \
        *(uint4*)&u.k.As[0][dst_off] = o;                                                     \
    }

    // ---- prologue: fill buffer 0 with k0=0 ----
    STAGE_B(0, 0)
    PACK_A(lr0, (const float4*)&x[ab0])
    PACK_A(lr1, (const float4*)&x[ab1])
    __syncthreads();

    int cur = 0;
    for (int k0 = 0; k0 < NFEAT; k0 += 32) {
        const int nxt = cur ^ 1;
        const bool have_next = (k0 + 32) < NFEAT;
        float4 p0, p1, q0, q1;
        if (have_next) {
            // Issue next tile's loads FIRST so latency hides under MFMA.
            const float4* xp0 = (const float4*)&x[ab0 + k0 + 32];
            const float4* xp1 = (const float4*)&x[ab1 + k0 + 32];
            p0 = xp0[0];
            p1 = xp0[1];
            q0 = xp1[0];
            q1 = xp1[1];
            STAGE_B(nxt, k0 + 32)
        }

        short8 af[4];
#pragma unroll
        for (int mt = 0; mt < 4; ++mt)
            af[mt] = *(const short8*)&u.k.As[cur][(wm * 64 + mt * 16 + fm) * 32 + fq * 8];
#pragma unroll
        for (int nt = 0; nt < 8; ++nt) {
            const short8 bfr = *(const short8*)&u.k.Bs[cur][(wn * 128 + nt * 16 + fm) * 32 + fq * 8];
#pragma unroll
            for (int mt = 0; mt < 4; ++mt)
                acc[mt][nt] = __builtin_amdgcn_mfma_f32_16x16x32_bf16(af[mt], bfr, acc[mt][nt], 0, 0, 0);
        }

        if (have_next) {
            uint4 o;
            o.x = pack_bf16_rh(p0.x, p0.y);
            o.y = pack_bf16_rh(p0.z, p0.w);
            o.z = pack_bf16_rh(p1.x, p1.y);
            o.w = pack_bf16_rh(p1.z, p1.w);
            *(uint4*)&u.k.As[nxt][lr0] = o;
            uint4 o2;
            o2.x = pack_bf16_rh(q0.x, q0.y);
            o2.y = pack_bf16_rh(q0.z, q0.w);
            o2.z = pack_bf16_rh(q1.x, q1.y);
            o2.w = pack_bf16_rh(q1.z, q1.w);
            *(uint4*)&u.k.As[nxt][lr1] = o2;
        }
        __syncthreads();   // drains vmcnt (B lds) + lgkmcnt (A write) for nxt
        cur = nxt;
    }

    // Epilogue (VERIFIED R0 4-pass): passes p=0..3 over 32-row groups.
    // Wave wm covers rows wm*64 + mt*16; pass p rows = (p>>1)*64 + (p&1)*32.
#pragma unroll
    for (int p = 0; p < 4; ++p) {
        __syncthreads();
        if ((w & 1) == (p >> 1)) {
#pragma unroll
            for (int mt2 = 0; mt2 < 2; ++mt2) {
                const int mt = (p & 1) * 2 + mt2;
#pragma unroll
                for (int nt = 0; nt < 8; ++nt)
#pragma unroll
                    for (int r = 0; r < 4; ++r)
                        u.Cs[(mt2 * 16 + fq * 4 + r) * 260 + wn * 128 + nt * 16 + fm] =
                            (short)f2bf(acc[mt][nt][r]);
            }
        }
        __syncthreads();
        // 32 rows x 256 cols: one wave handles one row/iter
#pragma unroll
        for (int kk = 0; kk < 8; ++kk) {
            const int idx = tid + kk * 256;
            const int lrow = idx >> 6;
            const int c4 = (idx & 63) << 2;
            const int grow = rowbase + p * 32 + lrow;
            const uint2 vv = *(const uint2*)&u.Cs[lrow * 260 + c4];
            const float f0 = bf2f_lo(vv.x), f1 = bf2f_hi(vv.x);
            const float f2 = bf2f_lo(vv.y), f3 = bf2f_hi(vv.y);
            const float4 A1 = *(const float4*)&a[c4];
            const float4 A2 = *(const float4*)&a[NCLASS + c4];
            float p1 = f0 * A1.x + f1 * A1.y + f2 * A1.z + f3 * A1.w;
            float p2 = f0 * A2.x + f1 * A2.y + f2 * A2.z + f3 * A2.w;
#pragma unroll
            for (int off = 1; off < 64; off <<= 1) {
                p1 += __shfl_xor(p1, off);
                p2 += __shfl_xor(p2, off);
            }
            if (grow < M) {
                *(uint2*)&hb[(size_t)grow * NCLASS + c4] = vv;
                if (lane == 0) {
                    s_row[grow] = p1;
                    s_col[grow] = p2;
                }
            }
        }
    }
}

// ---------------------------------------------------------------------------
// Aggregation + elu + log_softmax (VERIFIED). One wave per row; lane holds
// 4 features. e = exp(-lrelu(s_row[r] + s_col[c])) inline.
// ---------------------------------------------------------------------------
__global__ __launch_bounds__(256) void aggregate_kernel(const unsigned short* __restrict__ hb,
                                                        const int* __restrict__ bucket,
                                                        const int* __restrict__ cnt,
                                                        const float* __restrict__ s_row,
                                                        const float* __restrict__ s_col,
                                                        float* __restrict__ out, int n) {
    const int wave = (int)((blockIdx.x * (size_t)blockDim.x + threadIdx.x) >> 6);
    const int lane = threadIdx.x & 63;
    if (wave >= n) return;
    const int r = wave;
    const int jb = r << 6;
    const int je = jb + min(cnt[r], BCAP);
    const int fo = lane << 2;
    const float sr = s_row[r];

    float rowsum = 0.f;
    int j = jb;

#define EDGE_E(c) ({ const float _l = sr + s_col[c];                         \
                     const float _lr = _l > 0.f ? _l : NEG_SLOPE * _l;       \
                     __expf(-_lr); })

#ifdef HAVE_DOT2
    float ac0 = 0.f, ac1 = 0.f, ac2 = 0.f, ac3 = 0.f;
    for (; j + 3 < je; j += 4) {
        const int4 cv = *(const int4*)&bucket[j];
        const uint2 g0 = *(const uint2*)&hb[(size_t)cv.x * NCLASS + fo];
        const uint2 g1 = *(const uint2*)&hb[(size_t)cv.y * NCLASS + fo];
        const uint2 g2 = *(const uint2*)&hb[(size_t)cv.z * NCLASS + fo];
        const uint2 g3 = *(const uint2*)&hb[(size_t)cv.w * NCLASS + fo];
        const float e0 = EDGE_E(cv.x);
        const float e1 = EDGE_E(cv.y);
        const float e2 = EDGE_E(cv.z);
        const float e3 = EDGE_E(cv.w);
        const unsigned ep01 = pack_bf16_rh(e0, e1);
        const unsigned ep23 = pack_bf16_rh(e2, e3);
        rowsum += (e0 + e1) + (e2 + e3);
        ac0 = dot2bf(__builtin_amdgcn_perm(g1.x, g0.x, 0x05040100), ep01, ac0);
        ac1 = dot2bf(__builtin_amdgcn_perm(g1.x, g0.x, 0x07060302), ep01, ac1);
        ac2 = dot2bf(__builtin_amdgcn_perm(g1.y, g0.y, 0x05040100), ep01, ac2);
        ac3 = dot2bf(__builtin_amdgcn_perm(g1.y, g0.y, 0x07060302), ep01, ac3);
        ac0 = dot2bf(__builtin_amdgcn_perm(g3.x, g2.x, 0x05040100), ep23, ac0);
        ac1 = dot2bf(__builtin_amdgcn_perm(g3.x, g2.x, 0x07060302), ep23, ac1);
        ac2 = dot2bf(__builtin_amdgcn_perm(g3.y, g2.y, 0x05040100), ep23, ac2);
        ac3 = dot2bf(__builtin_amdgcn_perm(g3.y, g2.y, 0x07060302), ep23, ac3);
    }
    float4 acc = make_float4(ac0, ac1, ac2, ac3);
#else
    float4 acc = make_float4(0.f, 0.f, 0.f, 0.f);
    for (; j + 3 < je; j += 4) {
        const int4 cv = *(const int4*)&bucket[j];
        const uint2 g0 = *(const uint2*)&hb[(size_t)cv.x * NCLASS + fo];
        const uint2 g1 = *(const uint2*)&hb[(size_t)cv.y * NCLASS + fo];
        const uint2 g2 = *(const uint2*)&hb[(size_t)cv.z * NCLASS + fo];
        const uint2 g3 = *(const uint2*)&hb[(size_t)cv.w * NCLASS + fo];
        const float e0 = EDGE_E(cv.x);
        const float e1 = EDGE_E(cv.y);
        const float e2 = EDGE_E(cv.z);
        const float e3 = EDGE_E(cv.w);
        rowsum += (e0 + e1) + (e2 + e3);
        acc.x += e0 * bf2f_lo(g0.x) + e1 * bf2f_lo(g1.x) + e2 * bf2f_lo(g2.x) + e3 * bf2f_lo(g3.x);
        acc.y += e0 * bf2f_hi(g0.x) + e1 * bf2f_hi(g1.x) + e2 * bf2f_hi(g2.x) + e3 * bf2f_hi(g3.x);
        acc.z += e0 * bf2f_lo(g0.y) + e1 * bf2f_lo(g1.y) + e2 * bf2f_lo(g2.y) + e3 * bf2f_lo(g3.y);
        acc.w += e0 * bf2f_hi(g0.y) + e1 * bf2f_hi(g1.y) + e2 * bf2f_hi(g2.y) + e3 * bf2f_hi(g3.y);
    }
#endif
    for (; j < je; ++j) {
        const int c = bucket[j];
        const uint2 g = *(const uint2*)&hb[(size_t)c * NCLASS + fo];
        const float e = EDGE_E(c);
        rowsum += e;
        acc.x += e * bf2f_lo(g.x);
        acc.y += e * bf2f_hi(g.x);
        acc.z += e * bf2f_lo(g.y);
        acc.w += e * bf2f_hi(g.y);
    }

    const float inv = 1.f / rowsum;
    float v[4] = {acc.x * inv, acc.y * inv, acc.z * inv, acc.w * inv};
#pragma unroll
    for (int i = 0; i < 4; ++i)
        v[i] = v[i] > 0.f ? v[i] : __expf(v[i]) - 1.f;

    float m = fmaxf(fmaxf(v[0], v[1]), fmaxf(v[2], v[3]));
#pragma unroll
    for (int off = 32; off > 0; off >>= 1) m = fmaxf(m, __shfl_xor(m, off));
    float s = 0.f;
#pragma unroll
    for (int i = 0; i < 4; ++i) s += __expf(v[i] - m);
#pragma unroll
    for (int off = 32; off > 0; off >>= 1) s += __shfl_xor(s, off);
    const float lse = m + __logf(s);

    float4 o = make_float4(v[0] - lse, v[1] - lse, v[2] - lse, v[3] - lse);
    *(float4*)&out[(size_t)r * NCLASS + fo] = o;
}

// ---------------------------------------------------------------------------
extern "C" void kernel_launch(void* const* d_in, const int* in_sizes, int n_in,
                              void* d_out, int out_size, void* d_ws, size_t ws_size,
                              hipStream_t stream) {
    const float* x  = (const float*)d_in[0];
    const float* W  = (const float*)d_in[1];
    const float* a  = (const float*)d_in[2];
    const int* edge = (const int*)d_in[3];
    float* out = (float*)d_out;

    const int M = in_sizes[0] / NFEAT;         // 50000
    const int E = in_sizes[3] / 2;             // 850000
    const int* row = edge;
    const int* col = edge + E;

    char* ws = (char*)d_ws;
    size_t off = 0;
    auto carve = [&](size_t bytes) -> char* {
        char* p = ws + off;
        off = (off + bytes + 255) & ~(size_t)255;
        return p;
    };
    unsigned short* Wt = (unsigned short*)carve((size_t)NCLASS * NFEAT * sizeof(short));
    unsigned short* hb = (unsigned short*)carve((size_t)M * NCLASS * sizeof(short)); // 25.6MB
    int*   cursor   = (int*)carve((size_t)M * sizeof(int));
    float* s_row    = (float*)carve((size_t)M * sizeof(float));
    float* s_col    = (float*)carve((size_t)M * sizeof(float));
    int*   bucket   = (int*)carve((size_t)M * BCAP * sizeof(int));   // 12.8MB

    init_kernel<<<512, 256, 0, stream>>>(W, Wt, cursor, M);

    gemm_scatter_kernel<<<SBLK + GBLK, 256, 0, stream>>>(x, Wt, hb, a, s_row, s_col,
                                                         row, col, cursor, bucket, M, E);

    aggregate_kernel<<<(M + 3) / 4, 256, 0, stream>>>(hb, bucket, cursor, s_row, s_col, out, M);
}